// Round 11
// baseline (74.763 us; speedup 1.0000x reference)
//
#include <hip/hip_runtime.h>
#include <math.h>

#define BATCH 8192
#define DIM 4096

// ---------------------------------------------------------------------------
// Compile-time x-rotation constant tables:
//   X_l(beta) = P0 + sum_mu cos(mu*beta)*A_mu + sin(mu*beta)*B_mu
// Layout (495 floats): l=1 @0 (27), l=2 @27 (125), l=3 @152 (343)
// ---------------------------------------------------------------------------

struct FT { float v[495]; };

constexpr double csqrt(double x) {
  double g = x > 1.0 ? x : 1.0;
  for (int i = 0; i < 50; ++i) g = 0.5 * (g + x / g);
  return g;
}

constexpr void mmc(int n, const double* A, const double* B, double* C) {
  for (int i = 0; i < n; ++i)
    for (int j = 0; j < n; ++j) {
      double s = 0.0;
      for (int k = 0; k < n; ++k) s += A[i * n + k] * B[k * n + j];
      C[i * n + j] = s;
    }
}

constexpr FT compute_ft() {
  FT o{};
  for (int l = 1; l <= 3; ++l) {
    const int n = 2 * l + 1, nn = n * n;
    double JX[49] = {}, UR[49] = {}, UI[49] = {};
    for (int a = 0; a < n - 1; ++a) {
      double m = (double)(a - l);
      double v = 0.5 * csqrt((double)(l * (l + 1)) - m * (m + 1.0));
      JX[(a + 1) * n + a] = v;
      JX[a * n + (a + 1)] = v;
    }
    UR[l * n + l] = 1.0;
    const double s = csqrt(0.5);
    for (int mu = 1; mu <= l; ++mu) {
      double sg = (mu & 1) ? -1.0 : 1.0;
      UR[(l + mu) * n + (l - mu)] = s;
      UR[(l + mu) * n + (l + mu)] = s * sg;
      UI[(l - mu) * n + (l - mu)] = s;
      UI[(l - mu) * n + (l + mu)] = -s * sg;
    }
    double MR[49] = {}, MI[49] = {};
    mmc(n, UR, JX, MR);
    mmc(n, UI, JX, MI);
    double K[49] = {};
    for (int a = 0; a < n; ++a)
      for (int b = 0; b < n; ++b) {
        double acc = 0.0;
        for (int c = 0; c < n; ++c)
          acc += MI[a * n + c] * UR[b * n + c] - MR[a * n + c] * UI[b * n + c];
        K[a * n + b] = acc;
      }
    const double TH = 0.78539816339744830962;
    double S[49] = {}, P[49] = {}, T[49] = {};
    for (int i = 0; i < nn; ++i) S[i] = K[i] * (TH / 16.0);
    for (int i = 0; i < n; ++i) P[i * n + i] = 1.0;
    for (int t = 12; t >= 1; --t) {
      mmc(n, S, P, T);
      double inv = 1.0 / (double)t;
      for (int i = 0; i < nn; ++i) P[i] = T[i] * inv;
      for (int i = 0; i < n; ++i) P[i * n + i] += 1.0;
    }
    for (int q = 0; q < 4; ++q) {
      mmc(n, P, P, T);
      for (int i = 0; i < nn; ++i) P[i] = T[i];
    }
    double acc[7][49] = {};
    double Ek[49] = {}, Et[49] = {};
    for (int i = 0; i < n; ++i) Ek[i * n + i] = 1.0;
    const double r2 = csqrt(0.5);
    const double c8[8] = {1.0, r2, 0.0, -r2, -1.0, -r2, 0.0, r2};
    const double s8[8] = {0.0, r2, 1.0, r2, 0.0, -r2, -1.0, -r2};
    for (int k = 0; k < 8; ++k) {
      for (int i = 0; i < nn; ++i) acc[0][i] += 0.125 * Ek[i];
      for (int mu = 1; mu <= l; ++mu) {
        int a8 = (mu * k) & 7;
        double cc = 0.25 * c8[a8], ss = 0.25 * s8[a8];
        for (int i = 0; i < nn; ++i) {
          acc[2 * mu - 1][i] += cc * Ek[i];
          acc[2 * mu][i] += ss * Ek[i];
        }
      }
      mmc(n, Ek, P, Et);
      for (int i = 0; i < nn; ++i) Ek[i] = Et[i];
    }
    int base = (l == 1) ? 0 : ((l == 2) ? 27 : 152);
    for (int t = 0; t <= 2 * l; ++t)
      for (int i = 0; i < nn; ++i) o.v[base + t * nn + i] = (float)acc[t][i];
  }
  return o;
}

__device__ __constant__ FT c_tb = compute_ft();

typedef float vf4 __attribute__((ext_vector_type(4)));

__device__ __forceinline__ vf4 vfma4(float a, vf4 v, vf4 acc) { return acc + a * v; }

// ---------------------------------------------------------------------------
// Per-lane D-entry e (0..82); all hot indices resolve at compile time after
// unrolling (e is wave-uniform in its l-class; one class per wave).
// ---------------------------------------------------------------------------
__device__ __forceinline__ float entry_for(int e, float cb1, float cb2, float cb3,
                                           float sb1, float sb2, float sb3,
                                           float al, float ga) {
  int l, n, basec, i, j;
  if (e < 9)       { l = 1; n = 3; basec = 0;   int r = e;      i = r / 3; j = r - i * 3; }
  else if (e < 34) { l = 2; n = 5; basec = 27;  int r = e - 9;  i = r / 5; j = r - i * 5; }
  else             { l = 3; n = 7; basec = 152; int r = e - 34; i = r / 7; j = r - i * 7; }

  const float* C = c_tb.v + basec;
  const int ip = n - 1 - i, jp = n - 1 - j;
  const int nn = n * n;
  float xij = 0.f, xijp = 0.f, xipj = 0.f, xipjp = 0.f;
  #pragma unroll
  for (int tt = 0; tt < 7; ++tt) {
    if (tt <= 2 * l) {
      float coef;
      if (tt == 0) coef = 1.f;
      else if (tt == 1) coef = cb1;
      else if (tt == 2) coef = sb1;
      else if (tt == 3) coef = cb2;
      else if (tt == 4) coef = sb2;
      else if (tt == 5) coef = cb3;
      else coef = sb3;
      const float* M = C + tt * nn;
      xij   = fmaf(coef, M[i * n + j],   xij);
      xijp  = fmaf(coef, M[i * n + jp],  xijp);
      xipj  = fmaf(coef, M[ip * n + j],  xipj);
      xipjp = fmaf(coef, M[ip * n + jp], xipjp);
    }
  }
  float sa, ca, sg, cg;
  sincosf((float)(i - l) * al, &sa, &ca);
  sincosf((float)(j - l) * ga, &sg, &cg);
  return (ca * xij + sa * xipj) * cg - (ca * xijp + sa * xipjp) * sg;
}

// broadcast D entry k (0..63) held in lane k's register d
__device__ __forceinline__ float dget1(float d, int k) {
  return __builtin_bit_cast(
      float, __builtin_amdgcn_readlane(__builtin_bit_cast(int, d), k));
}

// ---------------------------------------------------------------------------
// Depth-2 segment-split: grid = BATCH/2 blocks x 256 threads (4 waves).
// Block covers rows rA = blockIdx and rB = rA + BATCH/2.
//   w0: l0 copy + l1 of BOTH rows (8 loads in flight)
//   w1: l2 of BOTH rows (10 loads in flight)
//   w2: l3 of rA (7 loads)     w3: l3 of rB (7 loads)
// No LDS, no barriers; loads first, per-lane D trig overlaps latency;
// row-A store burst overlaps row-B loads in w0/w1.
// ---------------------------------------------------------------------------
__global__ __launch_bounds__(256, 8) void rot_p2(
    const float* __restrict__ gamma, const float* __restrict__ beta,
    const float* __restrict__ alpha, const float* __restrict__ x,
    float* __restrict__ out) {
  const int lane = threadIdx.x & 63;
  const int wv = threadIdx.x >> 6;  // 0..3
  const size_t bA = (size_t)blockIdx.x;
  const size_t bB = bA + BATCH / 2;

  const vf4* __restrict__ xinA = (const vf4*)x + bA * 1024;
  const vf4* __restrict__ xinB = (const vf4*)x + bB * 1024;
  vf4* __restrict__ xoA = (vf4*)out + bA * 1024;
  vf4* __restrict__ xoB = (vf4*)out + bB * 1024;

  if (wv == 0) {
    // ---- loads: l0+l1 of A then B (8 vf4 in flight) ----
    vf4 a0 = xinA[lane];
    vf4 a1[3];
    #pragma unroll
    for (int j = 0; j < 3; ++j) a1[j] = xinA[64 + j * 64 + lane];
    vf4 q0 = xinB[lane];
    vf4 q1[3];
    #pragma unroll
    for (int j = 0; j < 3; ++j) q1[j] = xinB[64 + j * 64 + lane];
    asm volatile("" ::"v"(a0), "v"(a1[0]), "v"(a1[1]), "v"(a1[2]), "v"(q0),
                 "v"(q1[0]), "v"(q1[1]), "v"(q1[2]));

    // l=0 copy of A: only needs the oldest load
    __builtin_nontemporal_store(a0, &xoA[lane]);

    // ---- D build A (l=1: 9 entries) ----
    {
      const float al = alpha[bA], bt = beta[bA], ga = gamma[bA];
      float cb1, sb1;
      sincosf(bt, &sb1, &cb1);
      int e = lane < 9 ? lane : 8;
      const float d = entry_for(e, cb1, 0.f, 0.f, sb1, 0.f, 0.f, al, ga);
      #pragma unroll
      for (int i = 0; i < 3; ++i) {
        vf4 o = (vf4)(0.f);
        #pragma unroll
        for (int j = 0; j < 3; ++j) o = vfma4(dget1(d, i * 3 + j), a1[j], o);
        __builtin_nontemporal_store(o, &xoA[64 + i * 64 + lane]);
      }
    }
    // l=0 copy of B, then consume B
    __builtin_nontemporal_store(q0, &xoB[lane]);
    {
      const float al = alpha[bB], bt = beta[bB], ga = gamma[bB];
      float cb1, sb1;
      sincosf(bt, &sb1, &cb1);
      int e = lane < 9 ? lane : 8;
      const float d = entry_for(e, cb1, 0.f, 0.f, sb1, 0.f, 0.f, al, ga);
      #pragma unroll
      for (int i = 0; i < 3; ++i) {
        vf4 o = (vf4)(0.f);
        #pragma unroll
        for (int j = 0; j < 3; ++j) o = vfma4(dget1(d, i * 3 + j), q1[j], o);
        __builtin_nontemporal_store(o, &xoB[64 + i * 64 + lane]);
      }
    }
  } else if (wv == 1) {
    // ---- loads: l2 of A then B (10 vf4 in flight) ----
    vf4 a2[5], q2[5];
    #pragma unroll
    for (int j = 0; j < 5; ++j) a2[j] = xinA[256 + j * 64 + lane];
    #pragma unroll
    for (int j = 0; j < 5; ++j) q2[j] = xinB[256 + j * 64 + lane];
    asm volatile("" ::"v"(a2[0]), "v"(a2[1]), "v"(a2[2]), "v"(a2[3]),
                 "v"(a2[4]), "v"(q2[0]), "v"(q2[1]), "v"(q2[2]), "v"(q2[3]),
                 "v"(q2[4]));

    {
      const float al = alpha[bA], bt = beta[bA], ga = gamma[bA];
      float cb1, sb1;
      sincosf(bt, &sb1, &cb1);
      const float cb2 = cb1 * cb1 - sb1 * sb1, sb2 = 2.f * sb1 * cb1;
      int e = 9 + (lane < 25 ? lane : 24);
      const float d = entry_for(e, cb1, cb2, 0.f, sb1, sb2, 0.f, al, ga);
      #pragma unroll
      for (int i = 0; i < 5; ++i) {
        vf4 o = (vf4)(0.f);
        #pragma unroll
        for (int j = 0; j < 5; ++j) o = vfma4(dget1(d, i * 5 + j), a2[j], o);
        __builtin_nontemporal_store(o, &xoA[256 + i * 64 + lane]);
      }
    }
    {
      const float al = alpha[bB], bt = beta[bB], ga = gamma[bB];
      float cb1, sb1;
      sincosf(bt, &sb1, &cb1);
      const float cb2 = cb1 * cb1 - sb1 * sb1, sb2 = 2.f * sb1 * cb1;
      int e = 9 + (lane < 25 ? lane : 24);
      const float d = entry_for(e, cb1, cb2, 0.f, sb1, sb2, 0.f, al, ga);
      #pragma unroll
      for (int i = 0; i < 5; ++i) {
        vf4 o = (vf4)(0.f);
        #pragma unroll
        for (int j = 0; j < 5; ++j) o = vfma4(dget1(d, i * 5 + j), q2[j], o);
        __builtin_nontemporal_store(o, &xoB[256 + i * 64 + lane]);
      }
    }
  } else {
    // ---- w2: l3 of rA; w3: l3 of rB (7 vf4 each) ----
    const size_t b = (wv == 2) ? bA : bB;
    const vf4* __restrict__ xin = (wv == 2) ? xinA : xinB;
    vf4* __restrict__ xo = (wv == 2) ? xoA : xoB;

    vf4 v3[7];
    #pragma unroll
    for (int j = 0; j < 7; ++j) v3[j] = xin[576 + j * 64 + lane];
    asm volatile("" ::"v"(v3[0]), "v"(v3[1]), "v"(v3[2]), "v"(v3[3]),
                 "v"(v3[4]), "v"(v3[5]), "v"(v3[6]));

    const float al = alpha[b], bt = beta[b], ga = gamma[b];
    float cb1, sb1;
    sincosf(bt, &sb1, &cb1);
    const float cb2 = cb1 * cb1 - sb1 * sb1, sb2 = 2.f * sb1 * cb1;
    const float cb3 = cb2 * cb1 - sb2 * sb1, sb3 = sb2 * cb1 + cb2 * sb1;
    int e = 34 + (lane < 49 ? lane : 48);
    const float d = entry_for(e, cb1, cb2, cb3, sb1, sb2, sb3, al, ga);

    #pragma unroll
    for (int i = 0; i < 7; ++i) {
      vf4 o = (vf4)(0.f);
      #pragma unroll
      for (int j = 0; j < 7; ++j) o = vfma4(dget1(d, i * 7 + j), v3[j], o);
      __builtin_nontemporal_store(o, &xo[576 + i * 64 + lane]);
    }
  }
}

extern "C" void kernel_launch(void* const* d_in, const int* in_sizes, int n_in,
                              void* d_out, int out_size, void* d_ws, size_t ws_size,
                              hipStream_t stream) {
  const float* gamma = (const float*)d_in[0];
  const float* beta  = (const float*)d_in[1];
  const float* alpha = (const float*)d_in[2];
  const float* x     = (const float*)d_in[3];
  float* out = (float*)d_out;

  rot_p2<<<BATCH / 2, 256, 0, stream>>>(gamma, beta, alpha, x, out);
}

// Round 12
// 44.180 us; speedup vs baseline: 1.6922x; 1.6922x over previous
//
#include <hip/hip_runtime.h>
#include <math.h>

#define BATCH 8192
#define DIM 4096

// ---------------------------------------------------------------------------
// Compile-time x-rotation constant tables:
//   X_l(beta) = P0 + sum_mu cos(mu*beta)*A_mu + sin(mu*beta)*B_mu
// Layout (495 floats): l=1 @0 (27), l=2 @27 (125), l=3 @152 (343)
// ---------------------------------------------------------------------------

struct FT { float v[495]; };

constexpr double csqrt(double x) {
  double g = x > 1.0 ? x : 1.0;
  for (int i = 0; i < 50; ++i) g = 0.5 * (g + x / g);
  return g;
}

constexpr void mmc(int n, const double* A, const double* B, double* C) {
  for (int i = 0; i < n; ++i)
    for (int j = 0; j < n; ++j) {
      double s = 0.0;
      for (int k = 0; k < n; ++k) s += A[i * n + k] * B[k * n + j];
      C[i * n + j] = s;
    }
}

constexpr FT compute_ft() {
  FT o{};
  for (int l = 1; l <= 3; ++l) {
    const int n = 2 * l + 1, nn = n * n;
    double JX[49] = {}, UR[49] = {}, UI[49] = {};
    for (int a = 0; a < n - 1; ++a) {
      double m = (double)(a - l);
      double v = 0.5 * csqrt((double)(l * (l + 1)) - m * (m + 1.0));
      JX[(a + 1) * n + a] = v;
      JX[a * n + (a + 1)] = v;
    }
    UR[l * n + l] = 1.0;
    const double s = csqrt(0.5);
    for (int mu = 1; mu <= l; ++mu) {
      double sg = (mu & 1) ? -1.0 : 1.0;
      UR[(l + mu) * n + (l - mu)] = s;
      UR[(l + mu) * n + (l + mu)] = s * sg;
      UI[(l - mu) * n + (l - mu)] = s;
      UI[(l - mu) * n + (l + mu)] = -s * sg;
    }
    double MR[49] = {}, MI[49] = {};
    mmc(n, UR, JX, MR);
    mmc(n, UI, JX, MI);
    double K[49] = {};
    for (int a = 0; a < n; ++a)
      for (int b = 0; b < n; ++b) {
        double acc = 0.0;
        for (int c = 0; c < n; ++c)
          acc += MI[a * n + c] * UR[b * n + c] - MR[a * n + c] * UI[b * n + c];
        K[a * n + b] = acc;
      }
    const double TH = 0.78539816339744830962;
    double S[49] = {}, P[49] = {}, T[49] = {};
    for (int i = 0; i < nn; ++i) S[i] = K[i] * (TH / 16.0);
    for (int i = 0; i < n; ++i) P[i * n + i] = 1.0;
    for (int t = 12; t >= 1; --t) {
      mmc(n, S, P, T);
      double inv = 1.0 / (double)t;
      for (int i = 0; i < nn; ++i) P[i] = T[i] * inv;
      for (int i = 0; i < n; ++i) P[i * n + i] += 1.0;
    }
    for (int q = 0; q < 4; ++q) {
      mmc(n, P, P, T);
      for (int i = 0; i < nn; ++i) P[i] = T[i];
    }
    double acc[7][49] = {};
    double Ek[49] = {}, Et[49] = {};
    for (int i = 0; i < n; ++i) Ek[i * n + i] = 1.0;
    const double r2 = csqrt(0.5);
    const double c8[8] = {1.0, r2, 0.0, -r2, -1.0, -r2, 0.0, r2};
    const double s8[8] = {0.0, r2, 1.0, r2, 0.0, -r2, -1.0, -r2};
    for (int k = 0; k < 8; ++k) {
      for (int i = 0; i < nn; ++i) acc[0][i] += 0.125 * Ek[i];
      for (int mu = 1; mu <= l; ++mu) {
        int a8 = (mu * k) & 7;
        double cc = 0.25 * c8[a8], ss = 0.25 * s8[a8];
        for (int i = 0; i < nn; ++i) {
          acc[2 * mu - 1][i] += cc * Ek[i];
          acc[2 * mu][i] += ss * Ek[i];
        }
      }
      mmc(n, Ek, P, Et);
      for (int i = 0; i < nn; ++i) Ek[i] = Et[i];
    }
    int base = (l == 1) ? 0 : ((l == 2) ? 27 : 152);
    for (int t = 0; t <= 2 * l; ++t)
      for (int i = 0; i < nn; ++i) o.v[base + t * nn + i] = (float)acc[t][i];
  }
  return o;
}

__device__ __constant__ FT c_tb = compute_ft();

typedef float vf4 __attribute__((ext_vector_type(4)));

__device__ __forceinline__ vf4 vfma4(float a, vf4 v, vf4 acc) { return acc + a * v; }

// ---------------------------------------------------------------------------
// Per-lane D-entry e (0..82); all hot indices resolve at compile time after
// unrolling (e is wave-uniform in its l-class; one class per wave).
// ---------------------------------------------------------------------------
__device__ __forceinline__ float entry_for(int e, float cb1, float cb2, float cb3,
                                           float sb1, float sb2, float sb3,
                                           float al, float ga) {
  int l, n, basec, i, j;
  if (e < 9)       { l = 1; n = 3; basec = 0;   int r = e;      i = r / 3; j = r - i * 3; }
  else if (e < 34) { l = 2; n = 5; basec = 27;  int r = e - 9;  i = r / 5; j = r - i * 5; }
  else             { l = 3; n = 7; basec = 152; int r = e - 34; i = r / 7; j = r - i * 7; }

  const float* C = c_tb.v + basec;
  const int ip = n - 1 - i, jp = n - 1 - j;
  const int nn = n * n;
  float xij = 0.f, xijp = 0.f, xipj = 0.f, xipjp = 0.f;
  #pragma unroll
  for (int tt = 0; tt < 7; ++tt) {
    if (tt <= 2 * l) {
      float coef;
      if (tt == 0) coef = 1.f;
      else if (tt == 1) coef = cb1;
      else if (tt == 2) coef = sb1;
      else if (tt == 3) coef = cb2;
      else if (tt == 4) coef = sb2;
      else if (tt == 5) coef = cb3;
      else coef = sb3;
      const float* M = C + tt * nn;
      xij   = fmaf(coef, M[i * n + j],   xij);
      xijp  = fmaf(coef, M[i * n + jp],  xijp);
      xipj  = fmaf(coef, M[ip * n + j],  xipj);
      xipjp = fmaf(coef, M[ip * n + jp], xipjp);
    }
  }
  float sa, ca, sg, cg;
  sincosf((float)(i - l) * al, &sa, &ca);
  sincosf((float)(j - l) * ga, &sg, &cg);
  return (ca * xij + sa * xipj) * cg - (ca * xijp + sa * xipjp) * sg;
}

// broadcast D entry k (0..63) held in lane k's register d
__device__ __forceinline__ float dget1(float d, int k) {
  return __builtin_bit_cast(
      float, __builtin_amdgcn_readlane(__builtin_bit_cast(int, d), k));
}

// ---------------------------------------------------------------------------
// Segment-split streamer (round-9 champion): 1 block = 192 threads = 3
// independent waves, one batch row per block. wave0: l=0 copy + l=1; wave1:
// l=2; wave2: l=3. One row per WG keeps the store footprint contiguous --
// deviations from this (r10 1-wave WGs, r11 2-row waves) inflated actual HBM
// traffic 60-75%. No LDS, no barriers; loads first, D trig overlaps latency.
// ---------------------------------------------------------------------------
__global__ __launch_bounds__(192) void rot_seg(
    const float* __restrict__ gamma, const float* __restrict__ beta,
    const float* __restrict__ alpha, const float* __restrict__ x,
    float* __restrict__ out) {
  const int tid = threadIdx.x;
  const int lane = tid & 63;
  const int wv = tid >> 6;  // 0,1,2
  const size_t b = (size_t)blockIdx.x;
  const vf4* __restrict__ xin = (const vf4*)x + b * 1024;
  vf4* __restrict__ xo = (vf4*)out + b * 1024;

  // angle scalar loads (uniform)
  const float al = alpha[b], bt = beta[b], ga = gamma[b];

  if (wv == 0) {
    // ---- loads first: l0 (1) + l1 (3) ----
    vf4 v0 = xin[lane];
    vf4 v1[3];
    #pragma unroll
    for (int j = 0; j < 3; ++j) v1[j] = xin[64 + j * 64 + lane];
    asm volatile("" ::"v"(v0), "v"(v1[0]), "v"(v1[1]), "v"(v1[2]));

    // l=0 copy needs no D: store as soon as v0 lands
    __builtin_nontemporal_store(v0, &xo[lane]);

    // ---- D build (l=1: 9 entries, lanes 0..8) ----
    float cb1, sb1;
    sincosf(bt, &sb1, &cb1);
    int e = lane < 9 ? lane : 8;
    const float d = entry_for(e, cb1, 0.f, 0.f, sb1, 0.f, 0.f, al, ga);

    #pragma unroll
    for (int i = 0; i < 3; ++i) {
      vf4 o = (vf4)(0.f);
      #pragma unroll
      for (int j = 0; j < 3; ++j) o = vfma4(dget1(d, i * 3 + j), v1[j], o);
      __builtin_nontemporal_store(o, &xo[64 + i * 64 + lane]);
    }
  } else if (wv == 1) {
    // ---- loads first: l2 (5) ----
    vf4 v2[5];
    #pragma unroll
    for (int j = 0; j < 5; ++j) v2[j] = xin[256 + j * 64 + lane];
    asm volatile("" ::"v"(v2[0]), "v"(v2[1]), "v"(v2[2]), "v"(v2[3]),
                 "v"(v2[4]));

    // ---- D build (l=2: 25 entries, lanes 0..24) ----
    float cb1, sb1;
    sincosf(bt, &sb1, &cb1);
    const float cb2 = cb1 * cb1 - sb1 * sb1, sb2 = 2.f * sb1 * cb1;
    int e = 9 + (lane < 25 ? lane : 24);
    const float d = entry_for(e, cb1, cb2, 0.f, sb1, sb2, 0.f, al, ga);

    #pragma unroll
    for (int i = 0; i < 5; ++i) {
      vf4 o = (vf4)(0.f);
      #pragma unroll
      for (int j = 0; j < 5; ++j) o = vfma4(dget1(d, i * 5 + j), v2[j], o);
      __builtin_nontemporal_store(o, &xo[256 + i * 64 + lane]);
    }
  } else {
    // ---- loads first: l3 (7) ----
    vf4 v3[7];
    #pragma unroll
    for (int j = 0; j < 7; ++j) v3[j] = xin[576 + j * 64 + lane];
    asm volatile("" ::"v"(v3[0]), "v"(v3[1]), "v"(v3[2]), "v"(v3[3]),
                 "v"(v3[4]), "v"(v3[5]), "v"(v3[6]));

    // ---- D build (l=3: 49 entries, lanes 0..48) ----
    float cb1, sb1;
    sincosf(bt, &sb1, &cb1);
    const float cb2 = cb1 * cb1 - sb1 * sb1, sb2 = 2.f * sb1 * cb1;
    const float cb3 = cb2 * cb1 - sb2 * sb1, sb3 = sb2 * cb1 + cb2 * sb1;
    int e = 34 + (lane < 49 ? lane : 48);
    const float d = entry_for(e, cb1, cb2, cb3, sb1, sb2, sb3, al, ga);

    #pragma unroll
    for (int i = 0; i < 7; ++i) {
      vf4 o = (vf4)(0.f);
      #pragma unroll
      for (int j = 0; j < 7; ++j) o = vfma4(dget1(d, i * 7 + j), v3[j], o);
      __builtin_nontemporal_store(o, &xo[576 + i * 64 + lane]);
    }
  }
}

extern "C" void kernel_launch(void* const* d_in, const int* in_sizes, int n_in,
                              void* d_out, int out_size, void* d_ws, size_t ws_size,
                              hipStream_t stream) {
  const float* gamma = (const float*)d_in[0];
  const float* beta  = (const float*)d_in[1];
  const float* alpha = (const float*)d_in[2];
  const float* x     = (const float*)d_in[3];
  float* out = (float*)d_out;

  rot_seg<<<BATCH, 192, 0, stream>>>(gamma, beta, alpha, x, out);
}